// Round 5
// baseline (1137.740 us; speedup 1.0000x reference)
//
#include <hip/hip_runtime.h>
#include <hip/hip_bf16.h>
#include <stdint.h>

#define N_ROWS 4096
#define DIM 512
#define M_COLS 50000
#define GTOT (M_COLS/16)   // 3125 column-groups of 16
#define SPLITS 8
#define TOPK 10

typedef __attribute__((ext_vector_type(8))) short bf16x8;
typedef __attribute__((ext_vector_type(4))) float f32x4;
typedef __attribute__((address_space(1))) const uint32_t gu32;
typedef __attribute__((address_space(3))) uint32_t lu32;

__device__ __forceinline__ float waveSum(float v){
  #pragma unroll
  for (int off=32; off>0; off>>=1) v += __shfl_xor(v, off, 64);
  return v;
}

__device__ __forceinline__ unsigned short f2bf(float x){
  __hip_bfloat16 h = __float2bfloat16(x);
  return *reinterpret_cast<unsigned short*>(&h);
}

// row-wise L2 normalize f32 -> bf16, one row per block, 128 threads x float4
__global__ __launch_bounds__(128) void norm_bf16_kernel(const float* __restrict__ in,
                                                        unsigned short* __restrict__ out){
  const int row = blockIdx.x;
  const int t = threadIdx.x;
  const float4 v = *reinterpret_cast<const float4*>(in + (size_t)row*DIM + t*4);
  float ss = v.x*v.x + v.y*v.y + v.z*v.z + v.w*v.w;
  ss = waveSum(ss);
  __shared__ float sred[2];
  if ((t & 63) == 0) sred[t>>6] = ss;
  __syncthreads();
  const float r = rsqrtf(sred[0] + sred[1]);
  ushort4 o;
  o.x = f2bf(v.x*r); o.y = f2bf(v.y*r); o.z = f2bf(v.z*r); o.w = f2bf(v.w*r);
  *reinterpret_cast<ushort4*>(out + (size_t)row*DIM + t*4) = o;
}

// per-row: S += (x.y)/(|x||y|); also writes normalized X as bf16
__global__ __launch_bounds__(128) void dotS_kernel(const float* __restrict__ X, const float* __restrict__ Y,
                                                   unsigned short* __restrict__ srcb, float* __restrict__ S_acc){
  const int row = blockIdx.x;
  const int t = threadIdx.x;
  const float4 x = *reinterpret_cast<const float4*>(X + (size_t)row*DIM + t*4);
  const float4 y = *reinterpret_cast<const float4*>(Y + (size_t)row*DIM + t*4);
  float ssx = x.x*x.x+x.y*x.y+x.z*x.z+x.w*x.w;
  float ssy = y.x*y.x+y.y*y.y+y.z*y.z+y.w*y.w;
  float sxy = x.x*y.x+x.y*y.y+x.z*y.z+x.w*y.w;
  ssx = waveSum(ssx); ssy = waveSum(ssy); sxy = waveSum(sxy);
  __shared__ float r0[2], r1[2], r2[2];
  if ((t&63)==0){ r0[t>>6]=ssx; r1[t>>6]=ssy; r2[t>>6]=sxy; }
  __syncthreads();
  const float tx = r0[0]+r0[1], ty = r1[0]+r1[1], txy = r2[0]+r2[1];
  const float rx = rsqrtf(tx);
  ushort4 o; o.x=f2bf(x.x*rx); o.y=f2bf(x.y*rx); o.z=f2bf(x.z*rx); o.w=f2bf(x.w*rx);
  *reinterpret_cast<ushort4*>(srcb + (size_t)row*DIM + t*4) = o;
  if (t == 0) atomicAdd(S_acc, txy * rsqrtf(tx*ty));
}

// Fused GEMM + per-row running top-10.
// Block: 4 waves x 16 rows = 64 rows; grid.y = split of the 3125 col-groups.
// A fragments in registers (full K=512). B tile (16 cols x 512) staged to LDS
// in [t][ksub][col] order so frag reads are lane-consecutive ds_read_b128.
__global__ __launch_bounds__(256) void mm_topk_kernel(const unsigned short* __restrict__ A,
                                                      const unsigned short* __restrict__ Z,
                                                      float* __restrict__ topk){
  __shared__ __align__(16) unsigned short tiles[2][16*DIM]; // 2 x 16KB
  const int l = threadIdx.x & 63;
  const int w = threadIdx.x >> 6;
  const int rb = blockIdx.x;
  const int sp = blockIdx.y;
  const int gps = (GTOT + SPLITS - 1)/SPLITS;
  const int g0 = sp*gps;
  const int g1 = min(GTOT, g0 + gps);

  // A frags: lane l holds row (l&15) of the wave's 16-row tile, k = (l>>4)*8 + j + 32t
  bf16x8 a[16];
  {
    const unsigned short* ap = A + (size_t)(rb*64 + w*16 + (l&15))*DIM + ((l>>4)*8);
    #pragma unroll
    for (int t=0; t<16; ++t) a[t] = *reinterpret_cast<const bf16x8*>(ap + 32*t);
  }

  // top-10 lists: lane (l&15)=i holds list[i] (ascending) of row (l>>4)*4+j in lst[j]
  float lst[4], thr[4];
  #pragma unroll
  for (int j=0;j<4;++j){ lst[j] = -__builtin_inff(); thr[j] = -__builtin_inff(); }

  auto stage = [&](int g, int b){
    const int c0 = g*16;
    #pragma unroll
    for (int q=0; q<4; ++q){
      const int i = w*4 + q;   // stages k-chunk t=i: 16 cols x 64B
      const unsigned short* src = Z + (size_t)(c0 + (l&15))*DIM + i*32 + (l>>4)*8;
      unsigned short* dst = &tiles[b][i*DIM]; // uniform base; HW writes +lane*16B
      __builtin_amdgcn_global_load_lds((gu32*)src, (lu32*)dst, 16, 0, 0);
    }
  };

  stage(g0, 0);
  for (int g=g0; g<g1; ++g){
    const int buf = (g - g0) & 1;
    __syncthreads();                       // stage(g) complete; compute(g-1) done block-wide
    if (g+1 < g1) stage(g+1, buf^1);       // prefetch in flight under compute
    f32x4 acc = {0.f,0.f,0.f,0.f};
    const unsigned short* tb = tiles[buf];
    #pragma unroll
    for (int t=0;t<16;++t){
      bf16x8 b = *reinterpret_cast<const bf16x8*>(tb + t*DIM + l*8);
      acc = __builtin_amdgcn_mfma_f32_16x16x32_bf16(a[t], b, acc, 0, 0, 0);
    }
    // top-10 update: acc[j] is score of row (l>>4)*4+j (col = l&15, irrelevant)
    #pragma unroll
    for (int j=0;j<4;++j){
      bool myc = acc[j] > thr[j];
      unsigned long long m = __ballot(myc);
      while (m){
        const unsigned long long grp = (m >> (l & 48)) & 0xFFFFull; // this group's pending bits
        if (grp){ // uniform within the 16-lane group; groups insert concurrently
          const int src = (l & 48) + __builtin_ctzll(grp);
          const float v = __shfl(acc[j], src, 64);
          float nxt = __shfl(lst[j], (l==63)?63:(l+1), 64);
          if ((l & 15) >= 9) nxt = __builtin_inff();
          lst[j] = fminf(nxt, fmaxf(lst[j], v));      // parallel sorted insert-drop-min
          thr[j] = __shfl(lst[j], l & 48, 64);        // new 10th-largest
          if (l == src) myc = false;
        }
        m = __ballot(myc);
      }
    }
  }

  if ((l & 15) < TOPK){
    #pragma unroll
    for (int j=0;j<4;++j){
      const int row = rb*64 + w*16 + (l>>4)*4 + j;
      topk[((size_t)row*SPLITS + sp)*TOPK + (l & 15)] = lst[j];
    }
  }
}

// merge per-split top-10 lists; one thread per (matmul,row); sum top-knn; atomicAdd
__global__ __launch_bounds__(256) void merge_kernel(const float* __restrict__ tk, const int* __restrict__ knnp,
                                                    float* __restrict__ FK){
  const int n = blockIdx.x*256 + threadIdx.x; // 0..8191
  float ls[TOPK];
  #pragma unroll
  for (int i=0;i<TOPK;++i) ls[i] = -__builtin_inff();
  const float* p = tk + (size_t)n*(SPLITS*TOPK);
  for (int i=0;i<SPLITS*TOPK;++i){
    const float v = p[i];
    if (v > ls[0]){
      ls[0] = v;
      #pragma unroll
      for (int k=0;k<TOPK-1;++k){
        if (ls[k] > ls[k+1]){ float tmp=ls[k]; ls[k]=ls[k+1]; ls[k+1]=tmp; }
      }
    }
  }
  const int kk = min(max(knnp[0],1),TOPK);
  float s = 0.f;
  #pragma unroll
  for (int i=0;i<TOPK;++i) if (i < kk) s += ls[TOPK-1-i];
  s = waveSum(s);
  __shared__ float red[4];
  if ((threadIdx.x & 63)==0) red[threadIdx.x>>6] = s;
  __syncthreads();
  if (threadIdx.x==0) atomicAdd(FK, red[0]+red[1]+red[2]+red[3]);
}

__global__ void finalize_kernel(const float* __restrict__ S_acc, const float* __restrict__ FK,
                                const int* __restrict__ knnp, float* __restrict__ out){
  const float k = (float)max(knnp[0],1);
  out[0] = (FK[0]/k - 2.0f*S_acc[0]) / (float)N_ROWS;
}

extern "C" void kernel_launch(void* const* d_in, const int* in_sizes, int n_in,
                              void* d_out, int out_size, void* d_ws, size_t ws_size,
                              hipStream_t stream){
  const float* X  = (const float*)d_in[0];  // X_trans
  const float* Y  = (const float*)d_in[1];  // Y_tgt
  const float* Zs = (const float*)d_in[2];  // Z_src
  const float* Zt = (const float*)d_in[3];  // Z_tgt
  const float* Bk = (const float*)d_in[4];  // back_emb
  const int* knn  = (const int*)d_in[5];

  char* ws = (char*)d_ws;
  float* S_acc = (float*)ws;
  float* FK    = (float*)(ws + 4);
  float* topk0 = (float*)(ws + 64);
  float* topk1 = topk0 + (size_t)N_ROWS*SPLITS*TOPK;
  unsigned short* srcb = (unsigned short*)(ws + 64 + 2*(size_t)N_ROWS*SPLITS*TOPK*4);
  unsigned short* bkb  = srcb + (size_t)N_ROWS*DIM;
  unsigned short* Zb   = bkb  + (size_t)N_ROWS*DIM;   // 50000x512 bf16, reused for Zt then Zs

  hipMemsetAsync(d_ws, 0, 64, stream);                       // zero S/FK accumulators
  dotS_kernel<<<N_ROWS, 128, 0, stream>>>(X, Y, srcb, S_acc);
  norm_bf16_kernel<<<N_ROWS, 128, 0, stream>>>(Bk, bkb);
  norm_bf16_kernel<<<M_COLS, 128, 0, stream>>>(Zt, Zb);
  mm_topk_kernel<<<dim3(N_ROWS/64, SPLITS), 256, 0, stream>>>(srcb, Zb, topk0); // src @ zt^T
  norm_bf16_kernel<<<M_COLS, 128, 0, stream>>>(Zs, Zb);
  mm_topk_kernel<<<dim3(N_ROWS/64, SPLITS), 256, 0, stream>>>(bkb, Zb, topk1);  // bk @ zs^T
  merge_kernel<<<(2*N_ROWS)/256, 256, 0, stream>>>(topk0, knn, FK);
  finalize_kernel<<<1, 1, 0, stream>>>(S_acc, FK, knn, (float*)d_out);
}

// Round 6
// 1088.725 us; speedup vs baseline: 1.0450x; 1.0450x over previous
//
#include <hip/hip_runtime.h>
#include <hip/hip_bf16.h>
#include <stdint.h>

#define N_ROWS 4096
#define DIM 512
#define M_COLS 50000
#define GTOT (M_COLS/16)   // 3125 column-groups of 16
#define SPLITS 16
#define TOPK 10

typedef __attribute__((ext_vector_type(8))) short bf16x8;
typedef __attribute__((ext_vector_type(4))) float f32x4;
typedef __attribute__((address_space(1))) const uint32_t gu32;
typedef __attribute__((address_space(3))) uint32_t lu32;

__device__ __forceinline__ float waveSum(float v){
  #pragma unroll
  for (int off=32; off>0; off>>=1) v += __shfl_xor(v, off, 64);
  return v;
}

__device__ __forceinline__ unsigned short f2bf(float x){
  __hip_bfloat16 h = __float2bfloat16(x);
  return *reinterpret_cast<unsigned short*>(&h);
}

// row-wise L2 normalize f32 -> bf16, one row per block, 128 threads x float4
__global__ __launch_bounds__(128) void norm_bf16_kernel(const float* __restrict__ in,
                                                        unsigned short* __restrict__ out){
  const int row = blockIdx.x;
  const int t = threadIdx.x;
  const float4 v = *reinterpret_cast<const float4*>(in + (size_t)row*DIM + t*4);
  float ss = v.x*v.x + v.y*v.y + v.z*v.z + v.w*v.w;
  ss = waveSum(ss);
  __shared__ float sred[2];
  if ((t & 63) == 0) sred[t>>6] = ss;
  __syncthreads();
  const float r = rsqrtf(sred[0] + sred[1]);
  ushort4 o;
  o.x = f2bf(v.x*r); o.y = f2bf(v.y*r); o.z = f2bf(v.z*r); o.w = f2bf(v.w*r);
  *reinterpret_cast<ushort4*>(out + (size_t)row*DIM + t*4) = o;
}

// per-row: S += (x.y)/(|x||y|); also writes normalized X as bf16
__global__ __launch_bounds__(128) void dotS_kernel(const float* __restrict__ X, const float* __restrict__ Y,
                                                   unsigned short* __restrict__ srcb, float* __restrict__ S_acc){
  const int row = blockIdx.x;
  const int t = threadIdx.x;
  const float4 x = *reinterpret_cast<const float4*>(X + (size_t)row*DIM + t*4);
  const float4 y = *reinterpret_cast<const float4*>(Y + (size_t)row*DIM + t*4);
  float ssx = x.x*x.x+x.y*x.y+x.z*x.z+x.w*x.w;
  float ssy = y.x*y.x+y.y*y.y+y.z*y.z+y.w*y.w;
  float sxy = x.x*y.x+x.y*y.y+x.z*y.z+x.w*y.w;
  ssx = waveSum(ssx); ssy = waveSum(ssy); sxy = waveSum(sxy);
  __shared__ float r0[2], r1[2], r2[2];
  if ((t&63)==0){ r0[t>>6]=ssx; r1[t>>6]=ssy; r2[t>>6]=sxy; }
  __syncthreads();
  const float tx = r0[0]+r0[1], ty = r1[0]+r1[1], txy = r2[0]+r2[1];
  const float rx = rsqrtf(tx);
  ushort4 o; o.x=f2bf(x.x*rx); o.y=f2bf(x.y*rx); o.z=f2bf(x.z*rx); o.w=f2bf(x.w*rx);
  *reinterpret_cast<ushort4*>(srcb + (size_t)row*DIM + t*4) = o;
  if (t == 0) atomicAdd(S_acc, txy * rsqrtf(tx*ty));
}

// Fused GEMM + per-row running top-10.
// Block: 4 waves x 32 rows = 128 rows; grid.y = split of the 3125 col-groups.
// Two A-fragment sets per wave (rows w*32+0..15 and +16..31) share each B read:
// 16 ds_read_b128 feed 32 MFMAs per iteration (2x arithmetic intensity vs 16-row).
__global__ __launch_bounds__(256, 2) void mm_topk_kernel(const unsigned short* __restrict__ A,
                                                         const unsigned short* __restrict__ Z,
                                                         float* __restrict__ topk){
  __shared__ __align__(16) unsigned short tiles[2][16*DIM]; // 2 x 16KB
  const int l = threadIdx.x & 63;
  const int w = threadIdx.x >> 6;
  const int rb = blockIdx.x;
  const int sp = blockIdx.y;
  const int gps = (GTOT + SPLITS - 1)/SPLITS;
  const int g0 = sp*gps;
  const int g1 = min(GTOT, g0 + gps);

  // A frags: lane l holds rows (l&15) and (l&15)+16 of the wave's 32-row tile
  bf16x8 a0[16], a1[16];
  {
    const unsigned short* ap = A + (size_t)(rb*128 + w*32 + (l&15))*DIM + ((l>>4)*8);
    #pragma unroll
    for (int t=0; t<16; ++t){
      a0[t] = *reinterpret_cast<const bf16x8*>(ap + 32*t);
      a1[t] = *reinterpret_cast<const bf16x8*>(ap + 16*DIM + 32*t);
    }
  }

  // top-10 lists: lane (l&15)=i holds list[i] (ascending) of row s*16+(l>>4)*4+j
  float lst[2][4], thr[2][4];
  #pragma unroll
  for (int s=0;s<2;++s)
    #pragma unroll
    for (int j=0;j<4;++j){ lst[s][j] = -__builtin_inff(); thr[s][j] = -__builtin_inff(); }

  auto stage = [&](int g, int b){
    const int c0 = g*16;
    #pragma unroll
    for (int q=0; q<4; ++q){
      const int i = w*4 + q;   // stages k-chunk t=i: 16 cols x 64B
      const unsigned short* src = Z + (size_t)(c0 + (l&15))*DIM + i*32 + (l>>4)*8;
      unsigned short* dst = &tiles[b][i*DIM]; // uniform base; HW writes +lane*16B
      __builtin_amdgcn_global_load_lds((gu32*)src, (lu32*)dst, 16, 0, 0);
    }
  };

  auto topk_update = [&](f32x4& acc, float* ls, float* th){
    #pragma unroll
    for (int j=0;j<4;++j){
      bool myc = acc[j] > th[j];
      unsigned long long m = __ballot(myc);
      while (m){
        const unsigned long long grp = (m >> (l & 48)) & 0xFFFFull;
        if (grp){ // uniform within the 16-lane group; groups insert concurrently
          const int src = (l & 48) + __builtin_ctzll(grp);
          const float v = __shfl(acc[j], src, 64);
          float nxt = __shfl(ls[j], (l==63)?63:(l+1), 64);
          if ((l & 15) >= 9) nxt = __builtin_inff();
          ls[j] = fminf(nxt, fmaxf(ls[j], v));      // parallel sorted insert-drop-min
          th[j] = __shfl(ls[j], l & 48, 64);        // new 10th-largest
          if (l == src) myc = false;
        }
        m = __ballot(myc);
      }
    }
  };

  stage(g0, 0);
  for (int g=g0; g<g1; ++g){
    const int buf = (g - g0) & 1;
    __syncthreads();                       // stage(g) complete; compute(g-1) done block-wide
    if (g+1 < g1) stage(g+1, buf^1);       // prefetch in flight under compute
    f32x4 acc0 = {0.f,0.f,0.f,0.f};
    f32x4 acc1 = {0.f,0.f,0.f,0.f};
    const unsigned short* tb = tiles[buf];
    #pragma unroll
    for (int t=0;t<16;++t){
      bf16x8 b = *reinterpret_cast<const bf16x8*>(tb + t*DIM + l*8);
      acc0 = __builtin_amdgcn_mfma_f32_16x16x32_bf16(a0[t], b, acc0, 0, 0, 0);
      acc1 = __builtin_amdgcn_mfma_f32_16x16x32_bf16(a1[t], b, acc1, 0, 0, 0);
    }
    topk_update(acc0, lst[0], thr[0]);
    topk_update(acc1, lst[1], thr[1]);
  }

  if ((l & 15) < TOPK){
    #pragma unroll
    for (int s=0;s<2;++s)
      #pragma unroll
      for (int j=0;j<4;++j){
        const int row = rb*128 + w*32 + s*16 + (l>>4)*4 + j;
        topk[((size_t)row*SPLITS + sp)*TOPK + (l & 15)] = lst[s][j];
      }
  }
}

// merge per-split top-10 lists; one thread per (matmul,row); sum top-knn; atomicAdd
__global__ __launch_bounds__(256) void merge_kernel(const float* __restrict__ tk, const int* __restrict__ knnp,
                                                    float* __restrict__ FK){
  const int n = blockIdx.x*256 + threadIdx.x; // 0..8191
  float ls[TOPK];
  #pragma unroll
  for (int i=0;i<TOPK;++i) ls[i] = -__builtin_inff();
  const float* p = tk + (size_t)n*(SPLITS*TOPK);
  for (int i=0;i<SPLITS*TOPK;++i){
    const float v = p[i];
    if (v > ls[0]){
      ls[0] = v;
      #pragma unroll
      for (int k=0;k<TOPK-1;++k){
        if (ls[k] > ls[k+1]){ float tmp=ls[k]; ls[k]=ls[k+1]; ls[k+1]=tmp; }
      }
    }
  }
  const int kk = min(max(knnp[0],1),TOPK);
  float s = 0.f;
  #pragma unroll
  for (int i=0;i<TOPK;++i) if (i < kk) s += ls[TOPK-1-i];
  s = waveSum(s);
  __shared__ float red[4];
  if ((threadIdx.x & 63)==0) red[threadIdx.x>>6] = s;
  __syncthreads();
  if (threadIdx.x==0) atomicAdd(FK, red[0]+red[1]+red[2]+red[3]);
}

__global__ void finalize_kernel(const float* __restrict__ S_acc, const float* __restrict__ FK,
                                const int* __restrict__ knnp, float* __restrict__ out){
  const float k = (float)max(knnp[0],1);
  out[0] = (FK[0]/k - 2.0f*S_acc[0]) / (float)N_ROWS;
}

extern "C" void kernel_launch(void* const* d_in, const int* in_sizes, int n_in,
                              void* d_out, int out_size, void* d_ws, size_t ws_size,
                              hipStream_t stream){
  const float* X  = (const float*)d_in[0];  // X_trans
  const float* Y  = (const float*)d_in[1];  // Y_tgt
  const float* Zs = (const float*)d_in[2];  // Z_src
  const float* Zt = (const float*)d_in[3];  // Z_tgt
  const float* Bk = (const float*)d_in[4];  // back_emb
  const int* knn  = (const int*)d_in[5];

  char* ws = (char*)d_ws;
  float* S_acc = (float*)ws;
  float* FK    = (float*)(ws + 4);
  float* topk0 = (float*)(ws + 64);
  float* topk1 = topk0 + (size_t)N_ROWS*SPLITS*TOPK;
  unsigned short* srcb = (unsigned short*)(ws + 64 + 2*(size_t)N_ROWS*SPLITS*TOPK*4);
  unsigned short* bkb  = srcb + (size_t)N_ROWS*DIM;
  unsigned short* Zb   = bkb  + (size_t)N_ROWS*DIM;   // 50000x512 bf16, reused for Zt then Zs

  hipMemsetAsync(d_ws, 0, 64, stream);                       // zero S/FK accumulators
  dotS_kernel<<<N_ROWS, 128, 0, stream>>>(X, Y, srcb, S_acc);
  norm_bf16_kernel<<<N_ROWS, 128, 0, stream>>>(Bk, bkb);
  norm_bf16_kernel<<<M_COLS, 128, 0, stream>>>(Zt, Zb);
  mm_topk_kernel<<<dim3(N_ROWS/128, SPLITS), 256, 0, stream>>>(srcb, Zb, topk0); // src @ zt^T
  norm_bf16_kernel<<<M_COLS, 128, 0, stream>>>(Zs, Zb);
  mm_topk_kernel<<<dim3(N_ROWS/128, SPLITS), 256, 0, stream>>>(bkb, Zb, topk1);  // bk @ zs^T
  merge_kernel<<<(2*N_ROWS)/256, 256, 0, stream>>>(topk0, knn, FK);
  finalize_kernel<<<1, 1, 0, stream>>>(S_acc, FK, knn, (float*)d_out);
}